// Round 1
// baseline (1687.189 us; speedup 1.0000x reference)
//
#include <hip/hip_runtime.h>

typedef unsigned short u16;
typedef unsigned int   u32;
typedef __attribute__((ext_vector_type(8))) short bf16x8;
typedef __attribute__((ext_vector_type(4))) float f32x4;

static __device__ __forceinline__ float bf2f(u16 u) {
  union { u32 i; float f; } v; v.i = ((u32)u) << 16; return v.f;
}
static __device__ __forceinline__ u16 f2bf(float f) {
  union { float f; u32 i; } v; v.f = f;
  u32 u = v.i;
  u32 r = (u + 0x7FFFu + ((u >> 16) & 1u)) >> 16;  // RNE
  return (u16)r;
}

// ---------------- f32 -> bf16 conversion, 8 elems/thread ----------------
__global__ __launch_bounds__(256) void cvt_bf16(const float* __restrict__ in,
                                                u16* __restrict__ out, long n) {
  long i = ((long)blockIdx.x * 256 + threadIdx.x) * 8;
  if (i >= n) return;
  float4 a = *(const float4*)(in + i);
  float4 b = *(const float4*)(in + i + 4);
  uint4 o;
  o.x = (u32)f2bf(a.x) | ((u32)f2bf(a.y) << 16);
  o.y = (u32)f2bf(a.z) | ((u32)f2bf(a.w) << 16);
  o.z = (u32)f2bf(b.x) | ((u32)f2bf(b.y) << 16);
  o.w = (u32)f2bf(b.z) | ((u32)f2bf(b.w) << 16);
  *(uint4*)(out + i) = o;
}

// ---------------- GEMM: C[r][c] = sum_k A[r][k] * W[c][k]  (nn.Linear) ----
// A: Mrows x 512 bf16 row-major, W: 512 x 512 bf16 row-major.
// Tile 128x128, BK=32, 4 waves (2x2 of 64x64), MFMA 16x16x32 bf16.
// MODE 0: store bf16 C. MODE 1: store fp32 C + bias[col] + resid[r][c].
#define LDA 40  // padded LDS row stride (elems): stride 80B -> <=2-way bank conflicts
template <int MODE>
__global__ __launch_bounds__(256) void gemm_bt(
    const u16* __restrict__ A, const u16* __restrict__ W,
    u16* __restrict__ Cb, float* __restrict__ Cf,
    const float* __restrict__ bias, const float* __restrict__ resid) {
  __shared__ __align__(16) u16 As[128 * LDA];
  __shared__ __align__(16) u16 Bs[128 * LDA];
  const int t = threadIdx.x;
  const int lane = t & 63, wave = t >> 6;
  const int wy = wave >> 1, wx = wave & 1;
  const int quad = lane >> 4, l15 = lane & 15;
  const long arow0 = (long)blockIdx.x * 128;
  const int  brow0 = blockIdx.y * 128;

  f32x4 acc[4][4];
#pragma unroll
  for (int i = 0; i < 4; i++)
#pragma unroll
    for (int j = 0; j < 4; j++) acc[i][j] = (f32x4){0.f, 0.f, 0.f, 0.f};

  for (int k0 = 0; k0 < 512; k0 += 32) {
    // stage 128x32 A-tile and B-tile (512 x 16B chunks each)
    for (int c = t; c < 512; c += 256) {
      const int row = c >> 2, seg = c & 3;
      uint4 va = *(const uint4*)(A + (arow0 + row) * 512 + k0 + seg * 8);
      uint4 vb = *(const uint4*)(W + (long)(brow0 + row) * 512 + k0 + seg * 8);
      *(uint4*)(As + row * LDA + seg * 8) = va;
      *(uint4*)(Bs + row * LDA + seg * 8) = vb;
    }
    __syncthreads();
    bf16x8 af[4], bfr[4];
#pragma unroll
    for (int mt = 0; mt < 4; mt++)
      af[mt] = *(const bf16x8*)(As + (wy * 64 + mt * 16 + l15) * LDA + quad * 8);
#pragma unroll
    for (int nt = 0; nt < 4; nt++)
      bfr[nt] = *(const bf16x8*)(Bs + (wx * 64 + nt * 16 + l15) * LDA + quad * 8);
#pragma unroll
    for (int mt = 0; mt < 4; mt++)
#pragma unroll
      for (int nt = 0; nt < 4; nt++)
        acc[mt][nt] = __builtin_amdgcn_mfma_f32_16x16x32_bf16(af[mt], bfr[nt],
                                                              acc[mt][nt], 0, 0, 0);
    __syncthreads();
  }

#pragma unroll
  for (int mt = 0; mt < 4; mt++) {
#pragma unroll
    for (int r = 0; r < 4; r++) {
      const long row = arow0 + wy * 64 + mt * 16 + quad * 4 + r;
#pragma unroll
      for (int nt = 0; nt < 4; nt++) {
        const int col = brow0 + wx * 64 + nt * 16 + l15;
        const float v = acc[mt][nt][r];
        if (MODE == 0) {
          Cb[row * 512 + col] = f2bf(v);
        } else {
          Cf[row * 512 + col] = v + bias[col] + resid[row * 512 + col];
        }
      }
    }
  }
}

// ---------------- attention: one block per sample n ----------------------
// Q/K/V rows n*17..n*17+16 (512 cols) in LDS; thread (h,i) does one query row.
__global__ __launch_bounds__(256) void attn(
    const u16* __restrict__ Q, const u16* __restrict__ K, const u16* __restrict__ V,
    const float* __restrict__ P, u16* __restrict__ CTX) {
  __shared__ __align__(16) u16 qs[17 * 512];
  __shared__ __align__(16) u16 ks[17 * 512];
  __shared__ __align__(16) u16 vs[17 * 512];
  __shared__ float Ps[17 * 17];
  const int t = threadIdx.x;
  const long base = (long)blockIdx.x * (17 * 512);
  for (int c = t; c < 1088; c += 256) {
    ((uint4*)qs)[c] = *(const uint4*)(Q + base + c * 8);
    ((uint4*)ks)[c] = *(const uint4*)(K + base + c * 8);
    ((uint4*)vs)[c] = *(const uint4*)(V + base + c * 8);
  }
  for (int c = t; c < 289; c += 256) Ps[c] = P[c];
  __syncthreads();
  if (t >= 136) return;
  const int h = t / 17, i = t % 17;
  const u16* qp = qs + i * 512 + h * 64;
  float qr[64];
#pragma unroll
  for (int m = 0; m < 64; m++) qr[m] = bf2f(qp[m]);
  float sc[17];
  float mx = -1e30f;
#pragma unroll
  for (int j = 0; j < 17; j++) {
    const u16* kp = ks + j * 512 + h * 64;
    float s = 0.f;
#pragma unroll
    for (int m = 0; m < 64; m++) s += qr[m] * bf2f(kp[m]);
    s = s * 0.125f + Ps[i * 17 + j];  // *1/sqrt(dk) then +P[d,e]
    sc[j] = s;
    mx = fmaxf(mx, s);
  }
  float sum = 0.f;
#pragma unroll
  for (int j = 0; j < 17; j++) { sc[j] = __expf(sc[j] - mx); sum += sc[j]; }
  const float inv = 1.f / sum;
  float accv[64];
#pragma unroll
  for (int m = 0; m < 64; m++) accv[m] = 0.f;
#pragma unroll
  for (int j = 0; j < 17; j++) {
    const float w = sc[j] * inv;
    const u16* vp = vs + j * 512 + h * 64;
#pragma unroll
    for (int m = 0; m < 64; m++) accv[m] += w * bf2f(vp[m]);
  }
  u16* cp = CTX + base + i * 512 + h * 64;
#pragma unroll
  for (int m = 0; m < 64; m++) cp[m] = f2bf(accv[m]);
}

// ---------------- LayerNorm over M=512, one wave per row ------------------
__global__ __launch_bounds__(256) void ln_row(
    const float* __restrict__ X, const float* __restrict__ gamma,
    const float* __restrict__ beta, float* __restrict__ out) {
  const int lane = threadIdx.x & 63, wave = threadIdx.x >> 6;
  const long row = (long)blockIdx.x * 4 + wave;
  const float* xp = X + row * 512 + lane * 8;
  float4 a = *(const float4*)(xp);
  float4 b = *(const float4*)(xp + 4);
  float s  = a.x + a.y + a.z + a.w + b.x + b.y + b.z + b.w;
  float sq = a.x*a.x + a.y*a.y + a.z*a.z + a.w*a.w +
             b.x*b.x + b.y*b.y + b.z*b.z + b.w*b.w;
#pragma unroll
  for (int off = 1; off < 64; off <<= 1) {
    s  += __shfl_xor(s, off);
    sq += __shfl_xor(sq, off);
  }
  const float mean = s * (1.f / 512.f);
  const float var  = sq * (1.f / 512.f) - mean * mean;
  const float rstd = rsqrtf(var + 1e-5f);
  const float4 g0 = *(const float4*)(gamma + lane * 8);
  const float4 g1 = *(const float4*)(gamma + lane * 8 + 4);
  const float4 b0 = *(const float4*)(beta + lane * 8);
  const float4 b1 = *(const float4*)(beta + lane * 8 + 4);
  float4 o0, o1;
  o0.x = (a.x - mean) * rstd * g0.x + b0.x;
  o0.y = (a.y - mean) * rstd * g0.y + b0.y;
  o0.z = (a.z - mean) * rstd * g0.z + b0.z;
  o0.w = (a.w - mean) * rstd * g0.w + b0.w;
  o1.x = (b.x - mean) * rstd * g1.x + b1.x;
  o1.y = (b.y - mean) * rstd * g1.y + b1.y;
  o1.z = (b.z - mean) * rstd * g1.z + b1.z;
  o1.w = (b.w - mean) * rstd * g1.w + b1.w;
  float* op = out + row * 512 + lane * 8;
  *(float4*)op = o0;
  *(float4*)(op + 4) = o1;
}

extern "C" void kernel_launch(void* const* d_in, const int* in_sizes, int n_in,
                              void* d_out, int out_size, void* d_ws, size_t ws_size,
                              hipStream_t stream) {
  const float* x     = (const float*)d_in[0];
  const float* P     = (const float*)d_in[1];
  const float* Wq    = (const float*)d_in[2];
  const float* Wk    = (const float*)d_in[3];
  const float* Wv    = (const float*)d_in[4];
  const float* Wo    = (const float*)d_in[5];
  const float* bo    = (const float*)d_in[6];
  const float* gamma = (const float*)d_in[7];
  const float* beta  = (const float*)d_in[8];

  const long SZ  = 139264L * 512;  // 71,303,168 elems (N*D x M)
  const long WSZ = 512L * 512;     // 262,144 elems

  // ws layout (bf16 elems), ~546 MB total with reuse:
  u16* xb   = (u16*)d_ws;        // x bf16; reused as ctx after QKV GEMMs
  u16* wqb  = xb + SZ;
  u16* wkb  = wqb + WSZ;
  u16* wvb  = wkb + WSZ;
  u16* wob  = wvb + WSZ;
  u16* Qb   = wob + WSZ;
  u16* Kb   = Qb + SZ;
  u16* Vb   = Kb + SZ;
  u16* ctxb = xb;                // x_bf16 dead after QKV projections
  float* outpre = (float*)Qb;    // overlays Q+K (dead after attention), 285 MB

  cvt_bf16<<<(int)(SZ / 2048), 256, 0, stream>>>(x, xb, SZ);
  cvt_bf16<<<(int)(WSZ / 2048), 256, 0, stream>>>(Wq, wqb, WSZ);
  cvt_bf16<<<(int)(WSZ / 2048), 256, 0, stream>>>(Wk, wkb, WSZ);
  cvt_bf16<<<(int)(WSZ / 2048), 256, 0, stream>>>(Wv, wvb, WSZ);
  cvt_bf16<<<(int)(WSZ / 2048), 256, 0, stream>>>(Wo, wob, WSZ);

  dim3 g(1088, 4);  // 139264/128 x 512/128
  gemm_bt<0><<<g, 256, 0, stream>>>(xb, wqb, Qb, nullptr, nullptr, nullptr);
  gemm_bt<0><<<g, 256, 0, stream>>>(xb, wkb, Kb, nullptr, nullptr, nullptr);
  gemm_bt<0><<<g, 256, 0, stream>>>(xb, wvb, Vb, nullptr, nullptr, nullptr);

  attn<<<8192, 256, 0, stream>>>(Qb, Kb, Vb, P, ctxb);

  gemm_bt<1><<<g, 256, 0, stream>>>(ctxb, wob, nullptr, outpre, bo, x);

  ln_row<<<34816, 256, 0, stream>>>(outpre, gamma, beta, (float*)d_out);
}